// Round 2
// baseline (388.174 us; speedup 1.0000x reference)
//
#include <hip/hip_runtime.h>
#include <hip/hip_bf16.h>

#define BATCH 8
#define NPTS  131072
#define DIM   32
#define NLAB  33
#define BPB1  256   // pass1 blocks per batch: 2048 total = 8 blocks/CU resident
#define BPB2  512   // pass2 blocks per batch: 4096 total

// ws float layout
#define OFF_CNT   0                    // BATCH*NLAB = 264
#define OFF_SUM   264                  // BATCH*NLAB*DIM = 8448
#define OFF_HNG   (264 + 8448)         // 264
#define WS_FLOATS (OFF_HNG + 264)

// Pass 1: per-batch label counts and per-label embedding sums.
// LDS accumulator transposed [d][l] (stride 33) so bank = (d + l) % 32:
// random labels spread atomic traffic across banks (R1: 0 conflicts measured).
__global__ __launch_bounds__(256) void pass1_kernel(
    const float* __restrict__ emb, const int* __restrict__ lab,
    float* __restrict__ gsum, float* __restrict__ gcnt) {
  const int b   = blockIdx.y;
  const int tid = threadIdx.x;
  __shared__ float s_sum[DIM * NLAB];
  __shared__ float s_cnt[NLAB];
  for (int i = tid; i < DIM * NLAB; i += 256) s_sum[i] = 0.f;
  if (tid < NLAB) s_cnt[tid] = 0.f;
  __syncthreads();

  const int sub   = tid >> 3;        // point slot within 32-point group
  const int lane8 = tid & 7;
  const int d0    = lane8 << 2;      // 4 dims per thread
  const size_t base = (size_t)b * NPTS;

  // exact trip count: NPTS / (BPB1*32) = 16 iterations, unrollable
  const int p0 = blockIdx.x * 32 + sub;
#pragma unroll
  for (int it = 0; it < NPTS / (BPB1 * 32); ++it) {
    const int p = p0 + it * (BPB1 * 32);
    const int l = lab[base + p];
    const float4 e = *(const float4*)(emb + (base + p) * DIM + d0);
    atomicAdd(&s_sum[(d0 + 0) * NLAB + l], e.x);
    atomicAdd(&s_sum[(d0 + 1) * NLAB + l], e.y);
    atomicAdd(&s_sum[(d0 + 2) * NLAB + l], e.z);
    atomicAdd(&s_sum[(d0 + 3) * NLAB + l], e.w);
    if (lane8 == 0) atomicAdd(&s_cnt[l], 1.0f);
  }
  __syncthreads();

  for (int i = tid; i < NLAB * DIM; i += 256) {
    const int l = i >> 5, d = i & 31;
    atomicAdd(&gsum[b * (NLAB * DIM) + i], s_sum[d * NLAB + l]);
  }
  if (tid < NLAB) atomicAdd(&gcnt[b * NLAB + tid], s_cnt[tid]);
}

// Pass 2: per-point distance-to-own-mean hinge, accumulated per label.
__global__ __launch_bounds__(256) void pass2_kernel(
    const float* __restrict__ emb, const int* __restrict__ lab,
    const float* __restrict__ gsum, const float* __restrict__ gcnt,
    float* __restrict__ ghinge) {
  const int b   = blockIdx.y;
  const int tid = threadIdx.x;
  __shared__ __align__(16) float s_mean[NLAB * DIM];  // [l][d]
  __shared__ float s_hinge[NLAB];

  for (int i = tid; i < NLAB * DIM; i += 256) {
    const int l = i >> 5;
    const float c = gcnt[b * NLAB + l];
    s_mean[i] = gsum[b * (NLAB * DIM) + i] / fmaxf(c, 1.0f);
  }
  if (tid < NLAB) s_hinge[tid] = 0.f;
  __syncthreads();

  const int sub   = tid >> 3;
  const int lane8 = tid & 7;
  const int d0    = lane8 << 2;
  const size_t base = (size_t)b * NPTS;
  const float4* smean4 = (const float4*)s_mean;

  const int p0 = blockIdx.x * 32 + sub;
#pragma unroll
  for (int it = 0; it < NPTS / (BPB2 * 32); ++it) {
    const int p = p0 + it * (BPB2 * 32);
    const int l = lab[base + p];
    const float4 e = *(const float4*)(emb + (base + p) * DIM + d0);
    const float4 m = smean4[l * 8 + lane8];
    const float dx = e.x - m.x, dy = e.y - m.y, dz = e.z - m.z, dw = e.w - m.w;
    float s = dx * dx + dy * dy + dz * dz + dw * dw;
    s += __shfl_xor(s, 1);
    s += __shfl_xor(s, 2);
    s += __shfl_xor(s, 4);
    if (lane8 == 0) {
      const float dist  = sqrtf(s + 1e-24f);
      const float hinge = fmaxf(dist - 0.1f, 0.f);
      atomicAdd(&s_hinge[l], hinge);
    }
  }
  __syncthreads();
  if (tid < NLAB) atomicAdd(&ghinge[b * NLAB + tid], s_hinge[tid]);
}

// Per-batch pull/push + final combine. One wave per batch, single block.
__global__ __launch_bounds__(512) void finish_kernel(
    const float* __restrict__ gsum, const float* __restrict__ gcnt,
    const float* __restrict__ ghinge, float* __restrict__ out) {
  const int tid = threadIdx.x;
  const int b   = tid >> 6;   // wave index = batch
  const int t   = tid & 63;
  __shared__ __align__(16) float s_mn[BATCH * 32 * DIM];  // normalized means, labels 1..32
  __shared__ float s_pl[BATCH], s_ps[BATCH];
  float* mn = s_mn + b * 32 * DIM;

  float cnt = 0.f;
  int   pres = 0;
  if (t < 32) {
    const int l = t + 1;
    cnt  = gcnt[b * NLAB + l];
    pres = (cnt > 0.f) ? 1 : 0;
    const float inv = 1.f / fmaxf(cnt, 1.f);
    float v[DIM];
    float n2 = 0.f;
    for (int d = 0; d < DIM; d++) {
      v[d] = gsum[b * (NLAB * DIM) + l * DIM + d] * inv;
      n2  += v[d] * v[d];
    }
    const float scale = 1.f / fmaxf(sqrtf(n2), 1e-12f);
    for (int d = 0; d < DIM; d++) mn[t * DIM + d] = v[d] * scale;
  }
  const unsigned long long bal = __ballot(pres);
  const unsigned int pmask32 = (unsigned int)(bal & 0xFFFFFFFFull);
  const int n_inst = __popc(pmask32);

  // pull
  float seg = 0.f;
  if (t < 32) seg = ghinge[b * NLAB + t + 1] / fmaxf(cnt, 1.f);
  for (int m = 1; m < 64; m <<= 1) seg += __shfl_xor(seg, m);
  const float pull = seg / ((float)n_inst + 1e-6f);

  __syncthreads();

  // push: 32x32 upper-triangle pairs over normalized means
  float hp_sum = 0.f, pm_sum = 0.f;
  for (int idx = t; idx < 1024; idx += 64) {
    const int i = idx >> 5, j = idx & 31;
    if (j > i && ((pmask32 >> i) & 1u) && ((pmask32 >> j) & 1u)) {
      const float4* a = (const float4*)(mn + i * DIM);
      const float4* c = (const float4*)(mn + j * DIM);
      float sq = 0.f;
      for (int q = 0; q < 8; q++) {
        const float4 av = a[q], cv = c[q];
        const float dx = av.x - cv.x, dy = av.y - cv.y;
        const float dz = av.z - cv.z, dw = av.w - cv.w;
        sq += dx * dx + dy * dy + dz * dz + dw * dw;
      }
      const float dmat = sqrtf(sq + 1e-24f);
      hp_sum += fmaxf(1.0f - dmat, 0.f);   // 2*DELTA_D = 1.0
      pm_sum += 1.f;
    }
  }
  for (int m = 1; m < 64; m <<= 1) {
    hp_sum += __shfl_xor(hp_sum, m);
    pm_sum += __shfl_xor(pm_sum, m);
  }
  const float push = (n_inst > 1) ? hp_sum / (pm_sum + 1e-6f) : 0.f;

  if (t == 0) { s_pl[b] = pull; s_ps[b] = push; }
  __syncthreads();

  if (tid < 64) {
    float pl = (t < BATCH) ? s_pl[t] : 0.f;
    float ps = (t < BATCH) ? s_ps[t] : 0.f;
    for (int m = 1; m < 64; m <<= 1) {
      pl += __shfl_xor(pl, m);
      ps += __shfl_xor(ps, m);
    }
    if (t == 0) {
      const float pull_m = pl / (float)BATCH;
      const float push_m = ps / (float)BATCH;
      out[0] = pull_m + push_m;
      out[1] = pull_m;
      out[2] = push_m;
    }
  }
}

extern "C" void kernel_launch(void* const* d_in, const int* in_sizes, int n_in,
                              void* d_out, int out_size, void* d_ws, size_t ws_size,
                              hipStream_t stream) {
  const float* emb = (const float*)d_in[0];
  const int*   lab = (const int*)d_in[1];
  float* out = (float*)d_out;
  float* ws  = (float*)d_ws;

  float* gcnt   = ws + OFF_CNT;
  float* gsum   = ws + OFF_SUM;
  float* ghinge = ws + OFF_HNG;

  hipMemsetAsync(d_ws, 0, WS_FLOATS * sizeof(float), stream);

  dim3 grid1(BPB1, BATCH);
  dim3 grid2(BPB2, BATCH);
  pass1_kernel<<<grid1, 256, 0, stream>>>(emb, lab, gsum, gcnt);
  pass2_kernel<<<grid2, 256, 0, stream>>>(emb, lab, gsum, gcnt, ghinge);
  finish_kernel<<<1, 512, 0, stream>>>(gsum, gcnt, ghinge, out);
}

// Round 3
// 346.569 us; speedup vs baseline: 1.1200x; 1.1200x over previous
//
#include <hip/hip_runtime.h>
#include <hip/hip_bf16.h>

#define BATCH 8
#define NPTS  131072
#define DIM   32
#define NLAB  33
#define CH    2048   // points per pass1 block
#define PC    256    // points per pass1 chunk
#define G1    (NPTS / CH)   // 64 pass1 blocks per batch
#define BPB2  512    // pass2 blocks per batch

// ws float layout
#define OFF_CNT   0                    // BATCH*NLAB = 264
#define OFF_SUM   264                  // BATCH*NLAB*DIM = 8448
#define OFF_PULL  (264 + 8448)         // 8
#define WS_FLOATS (OFF_PULL + 8)

// Pass 1: per-batch label counts + per-label embedding sums.
// R2 post-mortem: LDS atomic RMW ~3.4 cyc/lane-op/CU was the bottleneck
// (33.5M lane-atomics = 185us). Replace with block-local counting sort +
// register accumulation: 1 LDS atomic per point (counting) instead of 32.
__global__ __launch_bounds__(256) void pass1_kernel(
    const float* __restrict__ emb, const int* __restrict__ lab,
    float* __restrict__ gsum, float* __restrict__ gcnt) {
  const int b   = blockIdx.y;
  const int tid = threadIdx.x;
  __shared__ int s_lab[CH];       // all labels for this block, staged once
  __shared__ int s_cnt[NLAB];
  __shared__ int s_off[NLAB];
  __shared__ int s_sorted[PC];

  const size_t base = (size_t)b * NPTS + (size_t)blockIdx.x * CH;

  // stage labels (coalesced, fully pipelined)
#pragma unroll
  for (int r = 0; r < CH / 256; ++r)
    s_lab[r * 256 + tid] = lab[base + r * 256 + tid];

  // slot assignment: primary (l1,q1) covers labels 0..31;
  // label 32's 8 quads go to lane-31 threads of each half-wave (spread load).
  const int l1 = tid >> 3, q1 = tid & 7;
  const bool has2 = ((tid & 31) == 31);
  const int q2 = tid >> 5;
  float4 acc1 = {0.f, 0.f, 0.f, 0.f};
  float4 acc2 = {0.f, 0.f, 0.f, 0.f};
  int cnt_acc = 0;

  __syncthreads();

  for (int c = 0; c < CH / PC; ++c) {
    if (tid < NLAB) s_cnt[tid] = 0;
    __syncthreads();

    const int p = c * PC + tid;           // block-relative point id
    const int l = s_lab[p];
    const int pos = atomicAdd(&s_cnt[l], 1);
    __syncthreads();

    // exclusive prefix over 33 counts (wave 0)
    if (tid < 64) {
      int v = (tid < NLAB) ? s_cnt[tid] : 0;
#pragma unroll
      for (int d = 1; d < 64; d <<= 1) {
        int u = __shfl_up(v, d);
        if (tid >= d) v += u;
      }
      if (tid < NLAB) s_off[tid] = v - s_cnt[tid];
    }
    if (tid < NLAB) cnt_acc += s_cnt[tid];
    __syncthreads();

    s_sorted[s_off[l] + pos] = p;
    __syncthreads();

    // segmented register accumulation: thread (l,q) walks its label's segment
    {
      const int beg = s_off[l1], end = beg + s_cnt[l1];
      for (int j = beg; j < end; ++j) {
        const int pp = s_sorted[j];
        const float4 e = *(const float4*)(emb + (base + pp) * DIM + q1 * 4);
        acc1.x += e.x; acc1.y += e.y; acc1.z += e.z; acc1.w += e.w;
      }
      if (has2) {
        const int beg2 = s_off[32], end2 = beg2 + s_cnt[32];
        for (int j = beg2; j < end2; ++j) {
          const int pp = s_sorted[j];
          const float4 e = *(const float4*)(emb + (base + pp) * DIM + q2 * 4);
          acc2.x += e.x; acc2.y += e.y; acc2.z += e.z; acc2.w += e.w;
        }
      }
    }
    __syncthreads();   // protect s_cnt/s_sorted before next chunk
  }

  // epilogue: global accumulation
  {
    float* dst = gsum + ((size_t)b * NLAB + l1) * DIM + q1 * 4;
    atomicAdd(dst + 0, acc1.x);
    atomicAdd(dst + 1, acc1.y);
    atomicAdd(dst + 2, acc1.z);
    atomicAdd(dst + 3, acc1.w);
    if (has2) {
      float* dst2 = gsum + ((size_t)b * NLAB + 32) * DIM + q2 * 4;
      atomicAdd(dst2 + 0, acc2.x);
      atomicAdd(dst2 + 1, acc2.y);
      atomicAdd(dst2 + 2, acc2.z);
      atomicAdd(dst2 + 3, acc2.w);
    }
  }
  if (tid < NLAB) atomicAdd(&gcnt[b * NLAB + tid], (float)cnt_acc);
}

// Pass 2: per-point hinge, weight-folded into a per-thread register
// accumulator (w[l] = 1/(max(cnt,1)*(n_inst+1e-6)), 0 for label 0 / absent).
// Zero per-point LDS atomics; one global atomic per block.
__global__ __launch_bounds__(256) void pass2_kernel(
    const float* __restrict__ emb, const int* __restrict__ lab,
    const float* __restrict__ gsum, const float* __restrict__ gcnt,
    float* __restrict__ pullb) {
  const int b   = blockIdx.y;
  const int tid = threadIdx.x;
  __shared__ __align__(16) float s_mean[NLAB * DIM];  // [l][d]
  __shared__ float s_w[NLAB];
  __shared__ float s_red[4];

  for (int i = tid; i < NLAB * DIM; i += 256) {
    const int l = i >> 5;
    const float c = gcnt[b * NLAB + l];
    s_mean[i] = gsum[b * (NLAB * DIM) + i] / fmaxf(c, 1.0f);
  }
  if (tid < 64) {
    const float c = (tid < NLAB) ? gcnt[b * NLAB + tid] : 0.f;
    const int pres = (tid >= 1 && tid < NLAB && c > 0.f) ? 1 : 0;
    const unsigned long long bal = __ballot(pres);
    const float n_inst = (float)__popcll(bal);
    if (tid < NLAB)
      s_w[tid] = pres ? 1.f / (fmaxf(c, 1.f) * (n_inst + 1e-6f)) : 0.f;
  }
  __syncthreads();

  const int sub   = tid >> 3;
  const int lane8 = tid & 7;
  const int d0    = lane8 << 2;
  const size_t base = (size_t)b * NPTS;
  const float4* smean4 = (const float4*)s_mean;

  float wacc = 0.f;
  const int p0 = blockIdx.x * 32 + sub;
#pragma unroll
  for (int it = 0; it < NPTS / (BPB2 * 32); ++it) {
    const int p = p0 + it * (BPB2 * 32);
    const int l = lab[base + p];
    const float4 e = *(const float4*)(emb + (base + p) * DIM + d0);
    const float4 m = smean4[l * 8 + lane8];
    const float dx = e.x - m.x, dy = e.y - m.y, dz = e.z - m.z, dw = e.w - m.w;
    float s = dx * dx + dy * dy + dz * dz + dw * dw;
    s += __shfl_xor(s, 1);
    s += __shfl_xor(s, 2);
    s += __shfl_xor(s, 4);
    if (lane8 == 0) {
      const float dist = sqrtf(s + 1e-24f);
      wacc += s_w[l] * fmaxf(dist - 0.1f, 0.f);
    }
  }
  // block reduce -> one global atomic
#pragma unroll
  for (int m = 1; m < 64; m <<= 1) wacc += __shfl_xor(wacc, m);
  if ((tid & 63) == 0) s_red[tid >> 6] = wacc;
  __syncthreads();
  if (tid == 0)
    atomicAdd(&pullb[b], s_red[0] + s_red[1] + s_red[2] + s_red[3]);
}

// Per-batch push + final combine. One wave per batch, single block.
__global__ __launch_bounds__(512) void finish_kernel(
    const float* __restrict__ gsum, const float* __restrict__ gcnt,
    const float* __restrict__ pullb, float* __restrict__ out) {
  const int tid = threadIdx.x;
  const int b   = tid >> 6;   // wave index = batch
  const int t   = tid & 63;
  __shared__ __align__(16) float s_mn[BATCH * 32 * DIM];
  __shared__ float s_ps[BATCH];
  float* mn = s_mn + b * 32 * DIM;

  int pres = 0;
  if (t < 32) {
    const int l = t + 1;
    const float cnt = gcnt[b * NLAB + l];
    pres = (cnt > 0.f) ? 1 : 0;
    const float inv = 1.f / fmaxf(cnt, 1.f);
    float v[DIM];
    float n2 = 0.f;
    for (int d = 0; d < DIM; d++) {
      v[d] = gsum[b * (NLAB * DIM) + l * DIM + d] * inv;
      n2  += v[d] * v[d];
    }
    const float scale = 1.f / fmaxf(sqrtf(n2), 1e-12f);
    for (int d = 0; d < DIM; d++) mn[t * DIM + d] = v[d] * scale;
  }
  const unsigned long long bal = __ballot(pres);
  const unsigned int pmask32 = (unsigned int)(bal & 0xFFFFFFFFull);
  const int n_inst = __popc(pmask32);

  __syncthreads();

  float hp_sum = 0.f, pm_sum = 0.f;
  for (int idx = t; idx < 1024; idx += 64) {
    const int i = idx >> 5, j = idx & 31;
    if (j > i && ((pmask32 >> i) & 1u) && ((pmask32 >> j) & 1u)) {
      const float4* a = (const float4*)(mn + i * DIM);
      const float4* c = (const float4*)(mn + j * DIM);
      float sq = 0.f;
      for (int q = 0; q < 8; q++) {
        const float4 av = a[q], cv = c[q];
        const float dx = av.x - cv.x, dy = av.y - cv.y;
        const float dz = av.z - cv.z, dw = av.w - cv.w;
        sq += dx * dx + dy * dy + dz * dz + dw * dw;
      }
      const float dmat = sqrtf(sq + 1e-24f);
      hp_sum += fmaxf(1.0f - dmat, 0.f);   // 2*DELTA_D = 1.0
      pm_sum += 1.f;
    }
  }
  for (int m = 1; m < 64; m <<= 1) {
    hp_sum += __shfl_xor(hp_sum, m);
    pm_sum += __shfl_xor(pm_sum, m);
  }
  const float push = (n_inst > 1) ? hp_sum / (pm_sum + 1e-6f) : 0.f;
  if (t == 0) s_ps[b] = push;
  __syncthreads();

  if (tid < 64) {
    float pl = (t < BATCH) ? pullb[t] : 0.f;
    float ps = (t < BATCH) ? s_ps[t] : 0.f;
#pragma unroll
    for (int m = 1; m < 64; m <<= 1) {
      pl += __shfl_xor(pl, m);
      ps += __shfl_xor(ps, m);
    }
    if (t == 0) {
      const float pull_m = pl / (float)BATCH;
      const float push_m = ps / (float)BATCH;
      out[0] = pull_m + push_m;
      out[1] = pull_m;
      out[2] = push_m;
    }
  }
}

extern "C" void kernel_launch(void* const* d_in, const int* in_sizes, int n_in,
                              void* d_out, int out_size, void* d_ws, size_t ws_size,
                              hipStream_t stream) {
  const float* emb = (const float*)d_in[0];
  const int*   lab = (const int*)d_in[1];
  float* out = (float*)d_out;
  float* ws  = (float*)d_ws;

  float* gcnt  = ws + OFF_CNT;
  float* gsum  = ws + OFF_SUM;
  float* pullb = ws + OFF_PULL;

  hipMemsetAsync(d_ws, 0, WS_FLOATS * sizeof(float), stream);

  dim3 grid1(G1, BATCH);
  dim3 grid2(BPB2, BATCH);
  pass1_kernel<<<grid1, 256, 0, stream>>>(emb, lab, gsum, gcnt);
  pass2_kernel<<<grid2, 256, 0, stream>>>(emb, lab, gsum, gcnt, pullb);
  finish_kernel<<<1, 512, 0, stream>>>(gsum, gcnt, pullb, out);
}

// Round 4
// 311.005 us; speedup vs baseline: 1.2481x; 1.1144x over previous
//
#include <hip/hip_runtime.h>
#include <hip/hip_bf16.h>

#define BATCH 8
#define NPTS  131072
#define DIM   32
#define NLAB  33
#define CH1   1024            // points per pass1 block
#define PC1   256             // points per pass1 chunk (staged in LDS)
#define G1X   (NPTS / CH1)    // 128 blocks per batch -> 1024 total = 4/CU
#define BPB2  512             // pass2 blocks per batch

// ws float layout
#define OFF_CNT   0                    // BATCH*NLAB = 264
#define OFF_SUM   264                  // BATCH*NLAB*DIM = 8448
#define OFF_PULL  (264 + 8448)         // 8
#define WS_FLOATS (OFF_PULL + 8)

// Pass 1: per-batch label counts + per-label embedding sums.
// R3 post-mortem: segment-walk gathered scattered 128B lines from GLOBAL with
// 2 blocks/CU -> latency-bound. Fix: stage the 32KB chunk in LDS (coalesced),
// walk segments from LDS; 1024 blocks = 4/CU.
__global__ __launch_bounds__(256) void pass1_kernel(
    const float* __restrict__ emb, const int* __restrict__ lab,
    float* __restrict__ gsum, float* __restrict__ gcnt) {
  const int b   = blockIdx.y;
  const int tid = threadIdx.x;
  __shared__ __align__(16) float s_emb[PC1 * DIM];   // 32 KB, stride 32 floats
  __shared__ int s_cnt[NLAB];
  __shared__ int s_off[NLAB];
  __shared__ int s_sorted[PC1];

  const size_t base_pt = (size_t)b * NPTS + (size_t)blockIdx.x * CH1;

  const int l1 = tid >> 3, q1 = tid & 7;     // primary slot: labels 0..31
  const bool has2 = ((tid & 31) == 31);      // 8 spread lanes handle label 32
  const int q2 = tid >> 5;
  float4 acc1 = {0.f, 0.f, 0.f, 0.f};
  float4 acc2 = {0.f, 0.f, 0.f, 0.f};
  int cnt_acc = 0;

  for (int c = 0; c < CH1 / PC1; ++c) {
    __syncthreads();                         // (A) close previous walk
    if (tid < NLAB) s_cnt[tid] = 0;
    const int myl = lab[base_pt + c * PC1 + tid];
    __syncthreads();                         // (B) reset visible

    // stage 256 points x 128B into LDS, fully coalesced (8 float4 per thread)
    const float4* gsrc = (const float4*)(emb + (base_pt + (size_t)c * PC1) * DIM);
    float4* ldst = (float4*)s_emb;
#pragma unroll
    for (int r = 0; r < 8; ++r) ldst[r * 256 + tid] = gsrc[r * 256 + tid];

    const int pos = atomicAdd(&s_cnt[myl], 1);
    __syncthreads();                         // (C) counts final + emb staged

    if (tid < 64) {                          // exclusive scan of 33 counts
      int v = (tid < NLAB) ? s_cnt[tid] : 0;
#pragma unroll
      for (int d = 1; d < 64; d <<= 1) {
        int u = __shfl_up(v, d);
        if (tid >= d) v += u;
      }
      if (tid < NLAB) s_off[tid] = v - s_cnt[tid];
    }
    __syncthreads();                         // (D) offsets visible

    s_sorted[s_off[myl] + pos] = tid;
    if (tid < NLAB) cnt_acc += s_cnt[tid];
    __syncthreads();                         // (E) sorted visible

    // register accumulation: thread (l,q) walks its label's segment in LDS
    {
      const int beg = s_off[l1], n = s_cnt[l1];
      const float4* se = (const float4*)s_emb;
      for (int j = 0; j < n; ++j) {
        const float4 e = se[s_sorted[beg + j] * 8 + q1];
        acc1.x += e.x; acc1.y += e.y; acc1.z += e.z; acc1.w += e.w;
      }
      if (has2) {
        const int beg2 = s_off[32], n2 = s_cnt[32];
        for (int j = 0; j < n2; ++j) {
          const float4 e = se[s_sorted[beg2 + j] * 8 + q2];
          acc2.x += e.x; acc2.y += e.y; acc2.z += e.z; acc2.w += e.w;
        }
      }
    }
  }

  // epilogue: global accumulation (one unique (l,q) slot per thread)
  {
    float* dst = gsum + ((size_t)b * NLAB + l1) * DIM + q1 * 4;
    atomicAdd(dst + 0, acc1.x);
    atomicAdd(dst + 1, acc1.y);
    atomicAdd(dst + 2, acc1.z);
    atomicAdd(dst + 3, acc1.w);
    if (has2) {
      float* dst2 = gsum + ((size_t)b * NLAB + 32) * DIM + q2 * 4;
      atomicAdd(dst2 + 0, acc2.x);
      atomicAdd(dst2 + 1, acc2.y);
      atomicAdd(dst2 + 2, acc2.z);
      atomicAdd(dst2 + 3, acc2.w);
    }
  }
  if (tid < NLAB) atomicAdd(&gcnt[b * NLAB + tid], (float)cnt_acc);
}

// Pass 2: per-point hinge, weight-folded into registers; one atomic per block.
// s_mean padded to stride 36: unpadded, every label row starts at bank 0 and
// the 8 random-label b128 reads/wave are 8-way same-bank conflicts.
__global__ __launch_bounds__(256) void pass2_kernel(
    const float* __restrict__ emb, const int* __restrict__ lab,
    const float* __restrict__ gsum, const float* __restrict__ gcnt,
    float* __restrict__ pullb) {
  const int b   = blockIdx.y;
  const int tid = threadIdx.x;
  __shared__ __align__(16) float s_mean[NLAB * 36];
  __shared__ float s_w[NLAB];
  __shared__ float s_red[4];

  for (int i = tid; i < NLAB * DIM; i += 256) {
    const int l = i >> 5, d = i & 31;
    const float c = gcnt[b * NLAB + l];
    s_mean[l * 36 + d] = gsum[b * (NLAB * DIM) + i] / fmaxf(c, 1.0f);
  }
  if (tid < 64) {
    const float c = (tid < NLAB) ? gcnt[b * NLAB + tid] : 0.f;
    const int pres = (tid >= 1 && tid < NLAB && c > 0.f) ? 1 : 0;
    const unsigned long long bal = __ballot(pres);
    const float n_inst = (float)__popcll(bal);
    if (tid < NLAB)
      s_w[tid] = pres ? 1.f / (fmaxf(c, 1.f) * (n_inst + 1e-6f)) : 0.f;
  }
  __syncthreads();

  const int sub   = tid >> 3;
  const int lane8 = tid & 7;
  const int d0    = lane8 << 2;
  const size_t base = (size_t)b * NPTS;

  float wacc = 0.f;
  const int p0 = blockIdx.x * 32 + sub;
#pragma unroll
  for (int it = 0; it < NPTS / (BPB2 * 32); ++it) {
    const int p = p0 + it * (BPB2 * 32);
    const int l = lab[base + p];
    const float4 e = *(const float4*)(emb + (base + p) * DIM + d0);
    const float4 m = *(const float4*)(s_mean + l * 36 + d0);
    const float dx = e.x - m.x, dy = e.y - m.y, dz = e.z - m.z, dw = e.w - m.w;
    float s = dx * dx + dy * dy + dz * dz + dw * dw;
    s += __shfl_xor(s, 1);
    s += __shfl_xor(s, 2);
    s += __shfl_xor(s, 4);
    if (lane8 == 0) {
      const float dist = sqrtf(s + 1e-24f);
      wacc += s_w[l] * fmaxf(dist - 0.1f, 0.f);
    }
  }
#pragma unroll
  for (int m = 1; m < 64; m <<= 1) wacc += __shfl_xor(wacc, m);
  if ((tid & 63) == 0) s_red[tid >> 6] = wacc;
  __syncthreads();
  if (tid == 0)
    atomicAdd(&pullb[b], s_red[0] + s_red[1] + s_red[2] + s_red[3]);
}

// Per-batch push + final combine. One wave per batch, single block.
__global__ __launch_bounds__(512) void finish_kernel(
    const float* __restrict__ gsum, const float* __restrict__ gcnt,
    const float* __restrict__ pullb, float* __restrict__ out) {
  const int tid = threadIdx.x;
  const int b   = tid >> 6;
  const int t   = tid & 63;
  __shared__ __align__(16) float s_mn[BATCH * 32 * DIM];
  __shared__ float s_ps[BATCH];
  float* mn = s_mn + b * 32 * DIM;

  int pres = 0;
  if (t < 32) {
    const int l = t + 1;
    const float cnt = gcnt[b * NLAB + l];
    pres = (cnt > 0.f) ? 1 : 0;
    const float inv = 1.f / fmaxf(cnt, 1.f);
    float v[DIM];
    float n2 = 0.f;
    for (int d = 0; d < DIM; d++) {
      v[d] = gsum[b * (NLAB * DIM) + l * DIM + d] * inv;
      n2  += v[d] * v[d];
    }
    const float scale = 1.f / fmaxf(sqrtf(n2), 1e-12f);
    for (int d = 0; d < DIM; d++) mn[t * DIM + d] = v[d] * scale;
  }
  const unsigned long long bal = __ballot(pres);
  const unsigned int pmask32 = (unsigned int)(bal & 0xFFFFFFFFull);
  const int n_inst = __popc(pmask32);

  __syncthreads();

  float hp_sum = 0.f, pm_sum = 0.f;
  for (int idx = t; idx < 1024; idx += 64) {
    const int i = idx >> 5, j = idx & 31;
    if (j > i && ((pmask32 >> i) & 1u) && ((pmask32 >> j) & 1u)) {
      const float4* a = (const float4*)(mn + i * DIM);
      const float4* c = (const float4*)(mn + j * DIM);
      float sq = 0.f;
      for (int q = 0; q < 8; q++) {
        const float4 av = a[q], cv = c[q];
        const float dx = av.x - cv.x, dy = av.y - cv.y;
        const float dz = av.z - cv.z, dw = av.w - cv.w;
        sq += dx * dx + dy * dy + dz * dz + dw * dw;
      }
      const float dmat = sqrtf(sq + 1e-24f);
      hp_sum += fmaxf(1.0f - dmat, 0.f);   // 2*DELTA_D = 1.0
      pm_sum += 1.f;
    }
  }
  for (int m = 1; m < 64; m <<= 1) {
    hp_sum += __shfl_xor(hp_sum, m);
    pm_sum += __shfl_xor(pm_sum, m);
  }
  const float push = (n_inst > 1) ? hp_sum / (pm_sum + 1e-6f) : 0.f;
  if (t == 0) s_ps[b] = push;
  __syncthreads();

  if (tid < 64) {
    float pl = (t < BATCH) ? pullb[t] : 0.f;
    float ps = (t < BATCH) ? s_ps[t] : 0.f;
#pragma unroll
    for (int m = 1; m < 64; m <<= 1) {
      pl += __shfl_xor(pl, m);
      ps += __shfl_xor(ps, m);
    }
    if (t == 0) {
      const float pull_m = pl / (float)BATCH;
      const float push_m = ps / (float)BATCH;
      out[0] = pull_m + push_m;
      out[1] = pull_m;
      out[2] = push_m;
    }
  }
}

extern "C" void kernel_launch(void* const* d_in, const int* in_sizes, int n_in,
                              void* d_out, int out_size, void* d_ws, size_t ws_size,
                              hipStream_t stream) {
  const float* emb = (const float*)d_in[0];
  const int*   lab = (const int*)d_in[1];
  float* out = (float*)d_out;
  float* ws  = (float*)d_ws;

  float* gcnt  = ws + OFF_CNT;
  float* gsum  = ws + OFF_SUM;
  float* pullb = ws + OFF_PULL;

  hipMemsetAsync(d_ws, 0, WS_FLOATS * sizeof(float), stream);

  dim3 grid1(G1X, BATCH);
  dim3 grid2(BPB2, BATCH);
  pass1_kernel<<<grid1, 256, 0, stream>>>(emb, lab, gsum, gcnt);
  pass2_kernel<<<grid2, 256, 0, stream>>>(emb, lab, gsum, gcnt, pullb);
  finish_kernel<<<1, 512, 0, stream>>>(gsum, gcnt, pullb, out);
}

// Round 5
// 279.599 us; speedup vs baseline: 1.3883x; 1.1123x over previous
//
#include <hip/hip_runtime.h>
#include <hip/hip_bf16.h>

#define BATCH 8
#define NPTS  131072
#define DIM   32
#define NLAB  33
#define G1X   128             // pass1 blocks per batch -> 1024 total = 4/CU
#define P1PTS 1024            // points per pass1 block (256 per wave, 8 steps)
#define BPB2  512             // pass2 blocks per batch

// ws float layout
#define OFF_CNT   0                    // BATCH*NLAB = 264
#define OFF_SUM   264                  // BATCH*NLAB*DIM = 8448
#define OFF_PULL  (264 + 8448)         // 8
#define WS_FLOATS (OFF_PULL + 8)

typedef short  bf16x8 __attribute__((ext_vector_type(8)));
typedef float  f32x4  __attribute__((ext_vector_type(4)));

static __device__ __forceinline__ short f2bf(float f) {
  __hip_bfloat16 h = __float2bfloat16(f);
  return *reinterpret_cast<short*>(&h);
}

// Pass 1: sums[l][d] = onehot(labels)^T @ E  via MFMA one-hot GEMM.
// R4 post-mortem: sort+walk was a divergent dependent-LDS chain behind 5
// barriers/chunk -> latency-bound at 32% occ. This version: wave-private
// staging (no barriers in hot loop), one-hot A built from shuffled labels,
// 6 mfma_f32_16x16x32_bf16 per 32 points, counts from the compare bits.
__global__ __launch_bounds__(256) void pass1_kernel(
    const float* __restrict__ emb, const int* __restrict__ lab,
    float* __restrict__ gsum, float* __restrict__ gcnt) {
  const int b    = blockIdx.y;
  const int tid  = threadIdx.x;
  const int w    = tid >> 6;
  const int lane = tid & 63;

  // wave-private transposed tile: st[d*33 + p], d=dim 0..31, p=point 0..31
  // write bank = (4*(i&7)... ) -> 2-way max (free); B-read bank = (n+8g+j)%32
  // -> 2-way max (free).
  __shared__ float s_stage[4][32 * 33];   // 16.9 KB
  __shared__ int   s_cnt4[4][NLAB];
  float* st = s_stage[w];

  const size_t base = (size_t)b * NPTS + (size_t)blockIdx.x * P1PTS + w * 256;

  const int m0 = lane & 15;      // A row (label within tile), B col (dim)
  const int g  = lane >> 4;      // k-group
  f32x4 acc[3][2];
#pragma unroll
  for (int t = 0; t < 3; ++t)
#pragma unroll
    for (int u = 0; u < 2; ++u) acc[t][u] = (f32x4){0.f, 0.f, 0.f, 0.f};
  int cnt0 = 0, cnt1 = 0, cnt2 = 0;

  // prologue: prefetch step 0
  float4 ld[4];
  int labv;
  {
    const float4* src = (const float4*)(emb + base * DIM);
#pragma unroll
    for (int r = 0; r < 4; ++r) ld[r] = src[lane + 64 * r];
    labv = lab[base + (lane & 31)];
  }

  for (int step = 0; step < 8; ++step) {
    // stage current step into wave-private LDS, transposed [dim][point]
#pragma unroll
    for (int r = 0; r < 4; ++r) {
      const int i = lane + 64 * r;
      const int p = i >> 3, d0 = (i & 7) * 4;
      st[(d0 + 0) * 33 + p] = ld[r].x;
      st[(d0 + 1) * 33 + p] = ld[r].y;
      st[(d0 + 2) * 33 + p] = ld[r].z;
      st[(d0 + 3) * 33 + p] = ld[r].w;
    }
    const int labv_c = labv;

    // prefetch next step (overlaps with compute below)
    if (step < 7) {
      const float4* src = (const float4*)(emb + (base + (step + 1) * 32) * DIM);
#pragma unroll
      for (int r = 0; r < 4; ++r) ld[r] = src[lane + 64 * r];
      labv = lab[base + (step + 1) * 32 + (lane & 31)];
    }

    // A fragments: one-hot, 3 label tiles; counts ride along as int adds
    bf16x8 a0, a1, a2;
#pragma unroll
    for (int j = 0; j < 8; ++j) {
      const int lj = __shfl(labv_c, g * 8 + j);
      const int h0 = (lj == m0), h1 = (lj == m0 + 16), h2 = (lj == m0 + 32);
      a0[j] = h0 ? (short)0x3F80 : (short)0;
      a1[j] = h1 ? (short)0x3F80 : (short)0;
      a2[j] = h2 ? (short)0x3F80 : (short)0;
      cnt0 += h0; cnt1 += h1; cnt2 += h2;
    }

    // B fragments: E[k][n] from LDS, n = m0 (+16), k = g*8+j
    bf16x8 b0, b1;
#pragma unroll
    for (int j = 0; j < 8; ++j) {
      b0[j] = f2bf(st[m0 * 33 + g * 8 + j]);
      b1[j] = f2bf(st[(m0 + 16) * 33 + g * 8 + j]);
    }

    acc[0][0] = __builtin_amdgcn_mfma_f32_16x16x32_bf16(a0, b0, acc[0][0], 0, 0, 0);
    acc[0][1] = __builtin_amdgcn_mfma_f32_16x16x32_bf16(a0, b1, acc[0][1], 0, 0, 0);
    acc[1][0] = __builtin_amdgcn_mfma_f32_16x16x32_bf16(a1, b0, acc[1][0], 0, 0, 0);
    acc[1][1] = __builtin_amdgcn_mfma_f32_16x16x32_bf16(a1, b1, acc[1][1], 0, 0, 0);
    acc[2][0] = __builtin_amdgcn_mfma_f32_16x16x32_bf16(a2, b0, acc[2][0], 0, 0, 0);
    acc[2][1] = __builtin_amdgcn_mfma_f32_16x16x32_bf16(a2, b1, acc[2][1], 0, 0, 0);
  }

  // counts: reduce across the 4 k-groups (lanes l, l+16, l+32, l+48)
  cnt0 += __shfl_xor(cnt0, 16); cnt0 += __shfl_xor(cnt0, 32);
  cnt1 += __shfl_xor(cnt1, 16); cnt1 += __shfl_xor(cnt1, 32);
  cnt2 += __shfl_xor(cnt2, 16); cnt2 += __shfl_xor(cnt2, 32);
  if (lane < 16)            s_cnt4[w][m0]      = cnt0;
  else if (lane < 32)       s_cnt4[w][m0 + 16] = cnt1;
  if (lane == 32)           s_cnt4[w][32]      = cnt2;

  // per-wave epilogue: dump accumulators into the (now free) staging buffer
  // as [label][dim] (33*32 = 1056 floats, exactly the buffer size).
  // D layout: row(label-in-tile) = g*4 + r, col(dim) = m0 (+16u).
#pragma unroll
  for (int t = 0; t < 2; ++t)
#pragma unroll
    for (int u = 0; u < 2; ++u)
#pragma unroll
      for (int r = 0; r < 4; ++r)
        st[(t * 16 + g * 4 + r) * DIM + m0 + 16 * u] = acc[t][u][r];
  if (lane < 16) {
    st[32 * DIM + m0]      = acc[2][0][0];
    st[32 * DIM + m0 + 16] = acc[2][1][0];
  }
  __syncthreads();

  // cross-wave reduce + global atomics (1056 + 33 per block)
  for (int i = tid; i < NLAB * DIM; i += 256) {
    const float v = s_stage[0][i] + s_stage[1][i] + s_stage[2][i] + s_stage[3][i];
    atomicAdd(&gsum[(size_t)b * (NLAB * DIM) + i], v);
  }
  if (tid < NLAB) {
    const int c = s_cnt4[0][tid] + s_cnt4[1][tid] + s_cnt4[2][tid] + s_cnt4[3][tid];
    atomicAdd(&gcnt[b * NLAB + tid], (float)c);
  }
}

// Pass 2: per-point hinge, weight-folded into registers; one atomic per block.
// R5: all 8 labels preloaded upfront -> kills the lab->mean dependent chain,
// 8-deep memory-level parallelism per thread.
__global__ __launch_bounds__(256) void pass2_kernel(
    const float* __restrict__ emb, const int* __restrict__ lab,
    const float* __restrict__ gsum, const float* __restrict__ gcnt,
    float* __restrict__ pullb) {
  const int b   = blockIdx.y;
  const int tid = threadIdx.x;
  __shared__ __align__(16) float s_mean[NLAB * 36];
  __shared__ float s_w[NLAB];
  __shared__ float s_red[4];

  for (int i = tid; i < NLAB * DIM; i += 256) {
    const int l = i >> 5, d = i & 31;
    const float c = gcnt[b * NLAB + l];
    s_mean[l * 36 + d] = gsum[b * (NLAB * DIM) + i] / fmaxf(c, 1.0f);
  }
  if (tid < 64) {
    const float c = (tid < NLAB) ? gcnt[b * NLAB + tid] : 0.f;
    const int pres = (tid >= 1 && tid < NLAB && c > 0.f) ? 1 : 0;
    const unsigned long long bal = __ballot(pres);
    const float n_inst = (float)__popcll(bal);
    if (tid < NLAB)
      s_w[tid] = pres ? 1.f / (fmaxf(c, 1.f) * (n_inst + 1e-6f)) : 0.f;
  }
  __syncthreads();

  const int sub   = tid >> 3;
  const int lane8 = tid & 7;
  const int d0    = lane8 << 2;
  const size_t base = (size_t)b * NPTS;
  const int p0 = blockIdx.x * 32 + sub;
  constexpr int NIT = NPTS / (BPB2 * 32);   // 8

  int labs[NIT];
#pragma unroll
  for (int it = 0; it < NIT; ++it)
    labs[it] = lab[base + p0 + it * (BPB2 * 32)];

  float wacc = 0.f;
#pragma unroll
  for (int it = 0; it < NIT; ++it) {
    const int p = p0 + it * (BPB2 * 32);
    const int l = labs[it];
    const float4 e = *(const float4*)(emb + (base + p) * DIM + d0);
    const float4 m = *(const float4*)(s_mean + l * 36 + d0);
    const float dx = e.x - m.x, dy = e.y - m.y, dz = e.z - m.z, dw = e.w - m.w;
    float s = dx * dx + dy * dy + dz * dz + dw * dw;
    s += __shfl_xor(s, 1);
    s += __shfl_xor(s, 2);
    s += __shfl_xor(s, 4);
    if (lane8 == 0) {
      const float dist = sqrtf(s + 1e-24f);
      wacc += s_w[l] * fmaxf(dist - 0.1f, 0.f);
    }
  }
#pragma unroll
  for (int m = 1; m < 64; m <<= 1) wacc += __shfl_xor(wacc, m);
  if ((tid & 63) == 0) s_red[tid >> 6] = wacc;
  __syncthreads();
  if (tid == 0)
    atomicAdd(&pullb[b], s_red[0] + s_red[1] + s_red[2] + s_red[3]);
}

// Per-batch push + final combine. One wave per batch, single block.
__global__ __launch_bounds__(512) void finish_kernel(
    const float* __restrict__ gsum, const float* __restrict__ gcnt,
    const float* __restrict__ pullb, float* __restrict__ out) {
  const int tid = threadIdx.x;
  const int b   = tid >> 6;
  const int t   = tid & 63;
  __shared__ __align__(16) float s_mn[BATCH * 32 * DIM];
  __shared__ float s_ps[BATCH];
  float* mn = s_mn + b * 32 * DIM;

  int pres = 0;
  if (t < 32) {
    const int l = t + 1;
    const float cnt = gcnt[b * NLAB + l];
    pres = (cnt > 0.f) ? 1 : 0;
    const float inv = 1.f / fmaxf(cnt, 1.f);
    float v[DIM];
    float n2 = 0.f;
    for (int d = 0; d < DIM; d++) {
      v[d] = gsum[b * (NLAB * DIM) + l * DIM + d] * inv;
      n2  += v[d] * v[d];
    }
    const float scale = 1.f / fmaxf(sqrtf(n2), 1e-12f);
    for (int d = 0; d < DIM; d++) mn[t * DIM + d] = v[d] * scale;
  }
  const unsigned long long bal = __ballot(pres);
  const unsigned int pmask32 = (unsigned int)(bal & 0xFFFFFFFFull);
  const int n_inst = __popc(pmask32);

  __syncthreads();

  float hp_sum = 0.f, pm_sum = 0.f;
  for (int idx = t; idx < 1024; idx += 64) {
    const int i = idx >> 5, j = idx & 31;
    if (j > i && ((pmask32 >> i) & 1u) && ((pmask32 >> j) & 1u)) {
      const float4* a = (const float4*)(mn + i * DIM);
      const float4* c = (const float4*)(mn + j * DIM);
      float sq = 0.f;
      for (int q = 0; q < 8; q++) {
        const float4 av = a[q], cv = c[q];
        const float dx = av.x - cv.x, dy = av.y - cv.y;
        const float dz = av.z - cv.z, dw = av.w - cv.w;
        sq += dx * dx + dy * dy + dz * dz + dw * dw;
      }
      const float dmat = sqrtf(sq + 1e-24f);
      hp_sum += fmaxf(1.0f - dmat, 0.f);   // 2*DELTA_D = 1.0
      pm_sum += 1.f;
    }
  }
  for (int m = 1; m < 64; m <<= 1) {
    hp_sum += __shfl_xor(hp_sum, m);
    pm_sum += __shfl_xor(pm_sum, m);
  }
  const float push = (n_inst > 1) ? hp_sum / (pm_sum + 1e-6f) : 0.f;
  if (t == 0) s_ps[b] = push;
  __syncthreads();

  if (tid < 64) {
    float pl = (t < BATCH) ? pullb[t] : 0.f;
    float ps = (t < BATCH) ? s_ps[t] : 0.f;
#pragma unroll
    for (int m = 1; m < 64; m <<= 1) {
      pl += __shfl_xor(pl, m);
      ps += __shfl_xor(ps, m);
    }
    if (t == 0) {
      const float pull_m = pl / (float)BATCH;
      const float push_m = ps / (float)BATCH;
      out[0] = pull_m + push_m;
      out[1] = pull_m;
      out[2] = push_m;
    }
  }
}

extern "C" void kernel_launch(void* const* d_in, const int* in_sizes, int n_in,
                              void* d_out, int out_size, void* d_ws, size_t ws_size,
                              hipStream_t stream) {
  const float* emb = (const float*)d_in[0];
  const int*   lab = (const int*)d_in[1];
  float* out = (float*)d_out;
  float* ws  = (float*)d_ws;

  float* gcnt  = ws + OFF_CNT;
  float* gsum  = ws + OFF_SUM;
  float* pullb = ws + OFF_PULL;

  hipMemsetAsync(d_ws, 0, WS_FLOATS * sizeof(float), stream);

  dim3 grid1(G1X, BATCH);
  dim3 grid2(BPB2, BATCH);
  pass1_kernel<<<grid1, 256, 0, stream>>>(emb, lab, gsum, gcnt);
  pass2_kernel<<<grid2, 256, 0, stream>>>(emb, lab, gsum, gcnt, pullb);
  finish_kernel<<<1, 512, 0, stream>>>(gsum, gcnt, pullb, out);
}